// Round 6
// baseline (562.396 us; speedup 1.0000x reference)
//
#include <hip/hip_runtime.h>
#include <stdint.h>

// VQ: inputs (16,64,64,64) f32 BCHW, codebook (1024,64) f32.
// out[0:65536] = argmin indices as float; out[65536:] = gathered rows, BCHW.
//
// r6: codebook quarters (256 codes) live in LDS, double-buffered via async
// global_load_lds from a PRE-SPLIT, PRE-SWIZZLED bf16 hi/lo copy in d_ws
// (prep kernel bakes the XOR swizzle into the ws byte order; main kernel's
// copy is linear -> rule-21 clean). Block = 64 pos x all 1024 codes -> no
// cross-block combine; finalize + exact rescreen + zqs epilogue in-block.
// All numerics r4/r5-validated: 3-pass hi/lo MFMA filter, packed (s|k) keys,
// BIAS keeps s>0, DELTA-gap rescreen with bit-exact numpy znorm + t/u/d.
#define NUM_K 1024
#define CDIM  64
#define NPOS  65536
#define NPB   64
#define DELTA 1e-4f    // 2*pack(3.1e-5) + grid(1.5e-5) + split(2e-6) < 1e-4
#define BIAS  0.25f    // s = cnorm+BIAS-2dot in [0.06,0.44] > 0

typedef __attribute__((ext_vector_type(8))) short short8;
typedef __attribute__((ext_vector_type(4))) float f32x4;
typedef unsigned int u32;
typedef __attribute__((address_space(3))) u32 lds_u32;
typedef const __attribute__((address_space(1))) u32 g_u32;

union U4S8 { uint4 u; short8 s; };

// ---- d_ws layout (bytes) ----
#define WS_CNORM 0         // 1024 f32 exact
#define WS_CNB   4096      // 1024 f32 (cnorm + BIAS)
#define WS_CB    8192      // 4 quarters * 65536: per q: hi 32768, lo 32768
                           // hi row kl: byte kl*128 + ((s*16)^((kl&7)*16))

__device__ __forceinline__ void cvt_pair(float f0, float f1,
                                         uint32_t& hp, uint32_t& lp) {
    uint32_t h;
    asm("v_cvt_pk_bf16_f32 %0, %1, %2" : "=v"(h) : "v"(f0), "v"(f1));
    float h0 = __uint_as_float(h << 16);
    float h1 = __uint_as_float(h & 0xFFFF0000u);
    float r0 = f0 - h0, r1 = f1 - h1;
    uint32_t l;
    asm("v_cvt_pk_bf16_f32 %0, %1, %2" : "=v"(l) : "v"(r0), "v"(r1));
    hp = h; lp = l;
}

__device__ __forceinline__ unsigned long long shflxor64(unsigned long long v, int off) {
    unsigned lo = (unsigned)v, hi = (unsigned)(v >> 32);
    lo = (unsigned)__shfl_xor((int)lo, off);
    hi = (unsigned)__shfl_xor((int)hi, off);
    return ((unsigned long long)hi << 32) | lo;
}

__device__ __forceinline__ void gload_lds16(const void* g, void* l) {
    __builtin_amdgcn_global_load_lds((g_u32*)g, (lds_u32*)l, 16, 0, 0);
}

#define RFMA4(acc, zb, v)                          \
    acc = fmaf(zv[(zb) + 0], v.x, acc);            \
    acc = fmaf(zv[(zb) + 1], v.y, acc);            \
    acc = fmaf(zv[(zb) + 2], v.z, acc);            \
    acc = fmaf(zv[(zb) + 3], v.w, acc);

// ---- kernel 1: cnorm (exact pairwise) + pre-split swizzled bf16 hi/lo ----
__global__ __launch_bounds__(256) void vq_prep_kernel(
    const float* __restrict__ cb, unsigned char* __restrict__ ws) {
#pragma clang fp contract(off)
    const int k = blockIdx.x * 256 + threadIdx.x;   // grid = 4 blocks
    const float4* row4 = (const float4*)(cb + k * CDIM);
    float v[CDIM];
#pragma unroll
    for (int i = 0; i < 16; ++i) {
        float4 t = row4[i];
        v[i * 4 + 0] = t.x; v[i * 4 + 1] = t.y;
        v[i * 4 + 2] = t.z; v[i * 4 + 3] = t.w;
    }
    // exact numpy pairwise cnorm (r2-validated)
    float r[8];
#pragma unroll
    for (int j = 0; j < 8; ++j) r[j] = v[j] * v[j];
#pragma unroll
    for (int i = 1; i < 8; ++i) {
#pragma unroll
        for (int j = 0; j < 8; ++j) {
            float s = v[i * 8 + j] * v[i * 8 + j];
            r[j] = r[j] + s;
        }
    }
    const float cn =
        ((r[0] + r[1]) + (r[2] + r[3])) + ((r[4] + r[5]) + (r[6] + r[7]));
    ((float*)(ws + WS_CNORM))[k] = cn;
    ((float*)(ws + WS_CNB))[k]   = cn + BIAS;

    // split + swizzled writes (quarter-local layout)
    const int q  = k >> 8, kl = k & 255;
    unsigned char* hi_base = ws + WS_CB + q * 65536;
    unsigned char* lo_base = hi_base + 32768;
#pragma unroll
    for (int s = 0; s < 8; ++s) {
        U4S8 H, L;
        uint32_t hp, lp;
        cvt_pair(v[s * 8 + 0], v[s * 8 + 1], hp, lp); H.u.x = hp; L.u.x = lp;
        cvt_pair(v[s * 8 + 2], v[s * 8 + 3], hp, lp); H.u.y = hp; L.u.y = lp;
        cvt_pair(v[s * 8 + 4], v[s * 8 + 5], hp, lp); H.u.z = hp; L.u.z = lp;
        cvt_pair(v[s * 8 + 6], v[s * 8 + 7], hp, lp); H.u.w = hp; L.u.w = lp;
        const int byte = kl * 128 + ((s * 16) ^ ((kl & 7) * 16));
        *(uint4*)(hi_base + byte) = H.u;
        *(uint4*)(lo_base + byte) = L.u;
    }
}

// ---- LDS layout (bytes) ----
#define LDS_QBUF 0         // 2 bufs * 65536 (hi 32768 | lo 32768)
#define LDS_ZHI  131072    // 64 pos * 128 B
#define LDS_ZLO  139264
#define LDS_WRED 147456    // 64 * 9 * 8 B (float2, pad 9)
#define LDS_AMBC 152064
#define LDS_AMBL 152068    // 64 int
#define LDS_SFIN 152324    // 64 int
#define LDS_ZSC  152592    // 8 waves * 64 f32 (16B aligned)
#define SMEM_SZ  154640

// ---- kernel 2: main ----
__global__ __launch_bounds__(512, 2) void vq_main_kernel(
    const float* __restrict__ in, const float* __restrict__ cb,
    const unsigned char* __restrict__ ws, float* __restrict__ out) {
#pragma clang fp contract(off)
    const int tid  = threadIdx.x;
    const int lane = tid & 63;
    const int wv   = tid >> 6;          // 0..7
    const int l15  = lane & 15;
    const int lg   = lane >> 4;         // 0..3
    const int n0g  = blockIdx.x * NPB;
    const int b    = n0g >> 12;
    const int hw0  = n0g & 4095;

    __shared__ __align__(16) unsigned char smem[SMEM_SZ];
    int*    ambcnt  = (int*)(smem + LDS_AMBC);
    int*    amblist = (int*)(smem + LDS_AMBL);
    int*    sfin    = (int*)(smem + LDS_SFIN);
    float*  zsc     = (float*)(smem + LDS_ZSC);
    float2* wred    = (float2*)(smem + LDS_WRED);
    const unsigned char* cbws = ws + WS_CB;
    const float* cnb_g  = (const float*)(ws + WS_CNB);
    const float* cnorm  = (const float*)(ws + WS_CNORM);

    if (tid == 0) *ambcnt = 0;

    // ---- issue async stage of quarter 0 into buf0 (flies during z-stage) ----
    {
        const unsigned char* src = cbws + wv * 8192 + lane * 16;
        unsigned char* dst = smem + LDS_QBUF + wv * 8192;
#pragma unroll
        for (int i = 0; i < 8; ++i)
            gload_lds16(src + i * 1024, dst + i * 1024);
    }

    // ---- stage z: 64 pos, bf16 hi/lo, swizzled (wave wv = dim-slot wv) ----
    {
        const int pos = lane;           // t = wv*64+lane -> slot wv, pos lane
        const int s   = wv;
        const float* zp = in + (((size_t)(b * CDIM + s * 8)) << 12) + hw0 + pos;
        float f[8];
#pragma unroll
        for (int j = 0; j < 8; ++j) f[j] = zp[(size_t)j << 12];
        U4S8 H, L;
        uint32_t hp, lp;
        cvt_pair(f[0], f[1], hp, lp); H.u.x = hp; L.u.x = lp;
        cvt_pair(f[2], f[3], hp, lp); H.u.y = hp; L.u.y = lp;
        cvt_pair(f[4], f[5], hp, lp); H.u.z = hp; L.u.z = lp;
        cvt_pair(f[6], f[7], hp, lp); H.u.w = hp; L.u.w = lp;
        const int byte = pos * 128 + ((s * 16) ^ ((pos & 7) * 16));
        *(uint4*)(smem + LDS_ZHI + byte) = H.u;
        *(uint4*)(smem + LDS_ZLO + byte) = L.u;
    }
    __syncthreads();    // drains q0 staging too

    const float finf = __uint_as_float(0x7F800000u);
    float m1[4] = {finf, finf, finf, finf};
    float m2[4] = {finf, finf, finf, finf};

    int buf = 0;
    for (int q = 0; q < 4; ++q) {
        if (q < 3) {    // async stage next quarter into other buffer
            const unsigned char* src = cbws + (q + 1) * 65536 + wv * 8192 + lane * 16;
            unsigned char* dst = smem + LDS_QBUF + (buf ^ 1) * 65536 + wv * 8192;
#pragma unroll
            for (int i = 0; i < 8; ++i)
                gload_lds16(src + i * 1024, dst + i * 1024);
        }

        // cb fragments for this wave's 2 ktiles (32 codes) -> registers
        const unsigned char* qb = smem + LDS_QBUF + buf * 65536;
        short8 afh[2][2], afl[2][2];
#pragma unroll
        for (int kt = 0; kt < 2; ++kt) {
            const int row = wv * 32 + kt * 16 + l15;
            const int rsw = (row & 7) * 16;
#pragma unroll
            for (int ks = 0; ks < 2; ++ks) {
                const int off = row * 128 + (((ks * 4 + lg) * 16) ^ rsw);
                afh[kt][ks] = *(const short8*)(qb + off);
                afl[kt][ks] = *(const short8*)(qb + 32768 + off);
            }
        }
        f32x4 cnv[2];
#pragma unroll
        for (int kt = 0; kt < 2; ++kt)
            cnv[kt] = *(const f32x4*)(cnb_g + q * 256 + wv * 32 + kt * 16 + lg * 4);

#pragma unroll
        for (int nt = 0; nt < 4; ++nt) {
            const int zr  = nt * 16 + l15;
            const int zsw = (zr & 7) * 16;
            short8 zh[2], zl[2];
#pragma unroll
            for (int ks = 0; ks < 2; ++ks) {
                const int off = zr * 128 + (((ks * 4 + lg) * 16) ^ zsw);
                zh[ks] = *(const short8*)(smem + LDS_ZHI + off);
                zl[ks] = *(const short8*)(smem + LDS_ZLO + off);
            }
            f32x4 a0 = {0.f, 0.f, 0.f, 0.f}, a1 = {0.f, 0.f, 0.f, 0.f};
            // kt0/kt1 interleaved (independent chains), 3-pass per ks
            a0 = __builtin_amdgcn_mfma_f32_16x16x32_bf16(afl[0][0], zh[0], a0, 0, 0, 0);
            a1 = __builtin_amdgcn_mfma_f32_16x16x32_bf16(afl[1][0], zh[0], a1, 0, 0, 0);
            a0 = __builtin_amdgcn_mfma_f32_16x16x32_bf16(afh[0][0], zl[0], a0, 0, 0, 0);
            a1 = __builtin_amdgcn_mfma_f32_16x16x32_bf16(afh[1][0], zl[0], a1, 0, 0, 0);
            a0 = __builtin_amdgcn_mfma_f32_16x16x32_bf16(afh[0][0], zh[0], a0, 0, 0, 0);
            a1 = __builtin_amdgcn_mfma_f32_16x16x32_bf16(afh[1][0], zh[0], a1, 0, 0, 0);
            a0 = __builtin_amdgcn_mfma_f32_16x16x32_bf16(afl[0][1], zh[1], a0, 0, 0, 0);
            a1 = __builtin_amdgcn_mfma_f32_16x16x32_bf16(afl[1][1], zh[1], a1, 0, 0, 0);
            a0 = __builtin_amdgcn_mfma_f32_16x16x32_bf16(afh[0][1], zl[1], a0, 0, 0, 0);
            a1 = __builtin_amdgcn_mfma_f32_16x16x32_bf16(afh[1][1], zl[1], a1, 0, 0, 0);
            a0 = __builtin_amdgcn_mfma_f32_16x16x32_bf16(afh[0][1], zh[1], a0, 0, 0, 0);
            a1 = __builtin_amdgcn_mfma_f32_16x16x32_bf16(afh[1][1], zh[1], a1, 0, 0, 0);

            const int kb0 = q * 256 + wv * 32 + lg * 4;
#pragma unroll
            for (int r = 0; r < 4; ++r) {
                float s = fmaf(-2.0f, a0[r], cnv[0][r]);
                float key = __uint_as_float(
                    (__float_as_uint(s) & 0xFFFFFC00u) | (uint32_t)(kb0 + r));
                m2[nt] = fminf(m2[nt], fmaxf(key, m1[nt]));
                m1[nt] = fminf(m1[nt], key);
            }
#pragma unroll
            for (int r = 0; r < 4; ++r) {
                float s = fmaf(-2.0f, a1[r], cnv[1][r]);
                float key = __uint_as_float(
                    (__float_as_uint(s) & 0xFFFFFC00u) | (uint32_t)(kb0 + 16 + r));
                m2[nt] = fminf(m2[nt], fmaxf(key, m1[nt]));
                m1[nt] = fminf(m1[nt], key);
            }
        }
        __syncthreads();    // drains next-quarter staging; frees buf
        buf ^= 1;
    }

    // ---- merge k-subgroups (lanes l, l+16, l+32, l+48), park in wred ----
#pragma unroll
    for (int nt = 0; nt < 4; ++nt) {
        float v1 = m1[nt], v2 = m2[nt];
#pragma unroll
        for (int off = 16; off <= 32; off <<= 1) {
            float o1 = __shfl_xor(v1, off);
            float o2 = __shfl_xor(v2, off);
            v2 = fminf(fminf(v2, o2), fmaxf(v1, o1));
            v1 = fminf(v1, o1);
        }
        if (lg == 0) {
            float2 w; w.x = v1; w.y = v2;
            wred[(nt * 16 + l15) * 9 + wv] = w;
        }
    }
    __syncthreads();

    // ---- cross-wave combine, zis write, ambiguity flag (tid<64) ----
    if (tid < 64) {
        float c1 = finf, c2 = finf;
#pragma unroll
        for (int w = 0; w < 8; ++w) {
            float2 v = wred[tid * 9 + w];
            c2 = fminf(fminf(c2, v.y), fmaxf(c1, v.x));
            c1 = fminf(c1, v.x);
        }
        const uint32_t u1 = __float_as_uint(c1);
        const int idx = (int)(u1 & 1023u);
        sfin[tid] = idx;
        out[n0g + tid] = (float)idx;
        const float v1 = __uint_as_float(u1 & 0xFFFFFC00u);
        const float v2 = __uint_as_float(__float_as_uint(c2) & 0xFFFFFC00u);
        if (v2 - v1 < DELTA) {
            int p = atomicAdd(ambcnt, 1);
            amblist[p] = tid;
        }
    }
    __syncthreads();

    // ---- exact rescreen, wave-parallel (r5-validated numerics) ----
    const int namb = *ambcnt;
    for (int i = wv; i < namb; i += 8) {
        const int n = amblist[i];
        float zc = in[(((size_t)(b * CDIM + lane)) << 12) + hw0 + n];
        // bit-exact numpy pairwise znorm via shfl (lanes 0-7 hold r[j])
        float sq = zc * zc;
        float accp = sq;
#pragma unroll
        for (int i2 = 1; i2 < 8; ++i2)
            accp = accp + __shfl(sq, i2 * 8 + (lane & 7));
        float t1 = accp + __shfl_xor(accp, 1);
        float t2 = t1 + __shfl_xor(t1, 2);
        float t3 = t2 + __shfl_xor(t2, 4);
        const float zn = __shfl(t3, 0);
        zsc[wv * 64 + lane] = zc;
        float zv[64];
#pragma unroll
        for (int q4 = 0; q4 < 16; ++q4) {
            float4 v = *(const float4*)(&zsc[wv * 64 + q4 * 4]);
            zv[q4 * 4 + 0] = v.x; zv[q4 * 4 + 1] = v.y;
            zv[q4 * 4 + 2] = v.z; zv[q4 * 4 + 3] = v.w;
        }
        unsigned long long bestk = ~0ull;
#pragma unroll
        for (int j = 0; j < 16; ++j) {
            const int k = j * 64 + lane;
            const float4* e = (const float4*)(cb + (size_t)k * CDIM);
            float a0 = 0.f, a1 = 0.f, a2 = 0.f, a3 = 0.f;
#pragma unroll
            for (int i2 = 0; i2 < 4; ++i2) {
                float4 v0 = e[i2 * 4 + 0];
                float4 v1 = e[i2 * 4 + 1];
                float4 v2 = e[i2 * 4 + 2];
                float4 v3 = e[i2 * 4 + 3];
                RFMA4(a0, i2 * 16 + 0,  v0)
                RFMA4(a1, i2 * 16 + 4,  v1)
                RFMA4(a2, i2 * 16 + 8,  v2)
                RFMA4(a3, i2 * 16 + 12, v3)
            }
            float dot = (a0 + a1) + (a2 + a3);
            float t = zn + cnorm[k];   // fl(znorm + cnorm)
            float u = 2.0f * dot;      // fl(2*dot)
            float d = t - u;           // fl(t - u)
            unsigned long long key =
                ((unsigned long long)__float_as_uint(d) << 10) | (unsigned)k;
            bestk = key < bestk ? key : bestk;
        }
#pragma unroll
        for (int off = 32; off >= 1; off >>= 1) {
            unsigned long long o = shflxor64(bestk, off);
            bestk = o < bestk ? o : bestk;
        }
        if (lane == 0) {
            const int idx = (int)(bestk & 1023u);
            sfin[n] = idx;
            out[n0g + n] = (float)idx;
        }
    }
    __syncthreads();

    // ---- zqs epilogue: gather -> LDS tile (overlay qbuf) -> coalesced BCHW ----
    float (*tile)[65] = (float (*)[65])(smem);
    if (tid < 256) {
        const int p = tid >> 2, q4 = tid & 3;
        const int idx = sfin[p];
        const float4* row = (const float4*)(cb + (size_t)idx * CDIM) + q4 * 4;
#pragma unroll
        for (int i = 0; i < 4; ++i) {
            float4 v = row[i];
            const int c = q4 * 16 + i * 4;
            tile[p][c + 0] = v.x; tile[p][c + 1] = v.y;
            tile[p][c + 2] = v.z; tile[p][c + 3] = v.w;
        }
    }
    __syncthreads();
    {
        float* zq = out + NPOS + (((size_t)b * CDIM) << 12) + hw0;
#pragma unroll
        for (int i = 0; i < 8; ++i) {
            const int c = i * 8 + wv;
            zq[((size_t)c << 12) + lane] = tile[lane][c];
        }
    }
}

extern "C" void kernel_launch(void* const* d_in, const int* in_sizes, int n_in,
                              void* d_out, int out_size, void* d_ws, size_t ws_size,
                              hipStream_t stream) {
    const float* in = (const float*)d_in[0];   // 16*64*64*64
    const float* cb = (const float*)d_in[1];   // 1024*64
    float* out = (float*)d_out;                // 65536 + 4194304
    unsigned char* ws = (unsigned char*)d_ws;  // ~270 KB used

    vq_prep_kernel<<<NUM_K / 256, 256, 0, stream>>>(cb, ws);
    vq_main_kernel<<<NPOS / NPB, 512, 0, stream>>>(in, cb, ws, out);
}

// Round 7
// 157.200 us; speedup vs baseline: 3.5776x; 3.5776x over previous
//
#include <hip/hip_runtime.h>
#include <stdint.h>

// VQ: inputs (16,64,64,64) f32 BCHW, codebook (1024,64) f32.
// out[0:65536] = argmin indices as float; out[65536:] = gathered rows, BCHW.
//
// r7: resource-disciplined rebuild of the validated bf16-split MFMA filter.
//  - 1024 blocks x 256 thr (4 waves). Wave owns 16 positions; z hi/lo frags
//    live in exactly 16 VGPR (built from global, no z staging LDS).
//  - codebook: pre-split pre-swizzled bf16 hi/lo in d_ws (prep kernel),
//    staged per 128-code chunk (32 KB) via linear global_load_lds,
//    double-buffered; 8 chunks cover all 1024 codes -> per-wave argmin is
//    complete after a 4-group shfl merge (no cross-wave combine).
//  - LDS 69.5 KB -> 2 blocks/CU; launch_bounds(256,2) -> VGPR cap 256,
//    design peak ~80 -> NO SPILL (r5/r6 died on 128-cap spills).
//  - numerics all r4/r6-validated: 3-pass hi/lo MFMA, packed (s|k) keys,
//    BIAS keeps s in [0.06,0.44], DELTA=1e-4 >= 2*pack(3.05e-5)+split+ref
//    -> exact rescreen (bit-exact numpy znorm, t/u/d order) decides ties.
#define NUM_K 1024
#define CDIM  64
#define NPOS  65536
#define NPB   64
#define DELTA 1e-4f
#define BIAS  0.25f

typedef __attribute__((ext_vector_type(8))) short short8;
typedef __attribute__((ext_vector_type(4))) float f32x4;
typedef unsigned int u32;
typedef __attribute__((address_space(3))) u32 lds_u32;
typedef const __attribute__((address_space(1))) u32 g_u32;

union U4S8 { uint4 u; short8 s; };

// ---- d_ws layout (bytes) ----
#define WS_CNORM 0         // 1024 f32 exact
#define WS_CNB   4096      // 1024 f32 (cnorm + BIAS)
#define WS_CB    8192      // 8 chunks * 32768: per chunk hi 16384 | lo 16384
                           // row kl (0..127): byte kl*128 + ((s*16)^((kl&7)*16))

__device__ __forceinline__ void cvt_pair(float f0, float f1,
                                         uint32_t& hp, uint32_t& lp) {
    uint32_t h;
    asm("v_cvt_pk_bf16_f32 %0, %1, %2" : "=v"(h) : "v"(f0), "v"(f1));
    float h0 = __uint_as_float(h << 16);
    float h1 = __uint_as_float(h & 0xFFFF0000u);
    float r0 = f0 - h0, r1 = f1 - h1;
    uint32_t l;
    asm("v_cvt_pk_bf16_f32 %0, %1, %2" : "=v"(l) : "v"(r0), "v"(r1));
    hp = h; lp = l;
}

__device__ __forceinline__ unsigned long long shflxor64(unsigned long long v, int off) {
    unsigned lo = (unsigned)v, hi = (unsigned)(v >> 32);
    lo = (unsigned)__shfl_xor((int)lo, off);
    hi = (unsigned)__shfl_xor((int)hi, off);
    return ((unsigned long long)hi << 32) | lo;
}

__device__ __forceinline__ void gload_lds16(const void* g, void* l) {
    __builtin_amdgcn_global_load_lds((g_u32*)g, (lds_u32*)l, 16, 0, 0);
}

// ---- kernel 1: cnorm (exact pairwise) + pre-split swizzled bf16 hi/lo ----
__global__ __launch_bounds__(256) void vq_prep_kernel(
    const float* __restrict__ cb, unsigned char* __restrict__ ws) {
#pragma clang fp contract(off)
    const int k = blockIdx.x * 256 + threadIdx.x;   // grid = 4 blocks
    const float4* row4 = (const float4*)(cb + k * CDIM);
    float v[CDIM];
#pragma unroll
    for (int i = 0; i < 16; ++i) {
        float4 t = row4[i];
        v[i * 4 + 0] = t.x; v[i * 4 + 1] = t.y;
        v[i * 4 + 2] = t.z; v[i * 4 + 3] = t.w;
    }
    float r[8];
#pragma unroll
    for (int j = 0; j < 8; ++j) r[j] = v[j] * v[j];
#pragma unroll
    for (int i = 1; i < 8; ++i) {
#pragma unroll
        for (int j = 0; j < 8; ++j) {
            float s = v[i * 8 + j] * v[i * 8 + j];
            r[j] = r[j] + s;
        }
    }
    const float cn =
        ((r[0] + r[1]) + (r[2] + r[3])) + ((r[4] + r[5]) + (r[6] + r[7]));
    ((float*)(ws + WS_CNORM))[k] = cn;
    ((float*)(ws + WS_CNB))[k]   = cn + BIAS;

    const int c  = k >> 7, kl = k & 127;
    unsigned char* hi_base = ws + WS_CB + c * 32768;
    unsigned char* lo_base = hi_base + 16384;
#pragma unroll
    for (int s = 0; s < 8; ++s) {
        U4S8 H, L;
        uint32_t hp, lp;
        cvt_pair(v[s * 8 + 0], v[s * 8 + 1], hp, lp); H.u.x = hp; L.u.x = lp;
        cvt_pair(v[s * 8 + 2], v[s * 8 + 3], hp, lp); H.u.y = hp; L.u.y = lp;
        cvt_pair(v[s * 8 + 4], v[s * 8 + 5], hp, lp); H.u.z = hp; L.u.z = lp;
        cvt_pair(v[s * 8 + 6], v[s * 8 + 7], hp, lp); H.u.w = hp; L.u.w = lp;
        const int byte = kl * 128 + ((s * 16) ^ ((kl & 7) * 16));
        *(uint4*)(hi_base + byte) = H.u;
        *(uint4*)(lo_base + byte) = L.u;
    }
}

// ---- LDS layout (bytes) ----
#define LDS_BUF  0         // 2 bufs * 32768 (hi 16384 | lo 16384)
#define LDS_CNB  65536     // 1024 f32
#define LDS_SFIN 69632     // 64 int
#define LDS_AMBC 69888
#define LDS_AMBL 69892     // 64 int
#define LDS_ZSC  70160     // 4 waves * 64 f32 (16B aligned)
#define SMEM_SZ  71184

// ---- kernel 2: main ----
__global__ __launch_bounds__(256, 2) void vq_main_kernel(
    const float* __restrict__ in, const float* __restrict__ cb,
    const unsigned char* __restrict__ ws, float* __restrict__ out) {
#pragma clang fp contract(off)
    const int tid  = threadIdx.x;
    const int lane = tid & 63;
    const int wv   = tid >> 6;          // 0..3
    const int l15  = lane & 15;
    const int lg   = lane >> 4;         // 0..3
    const int n0g  = blockIdx.x * NPB;
    const int b    = n0g >> 12;
    const int hw0  = n0g & 4095;

    __shared__ __align__(16) unsigned char smem[SMEM_SZ];
    float* cnb_l   = (float*)(smem + LDS_CNB);
    int*   sfin    = (int*)(smem + LDS_SFIN);
    int*   ambcnt  = (int*)(smem + LDS_AMBC);
    int*   amblist = (int*)(smem + LDS_AMBL);
    float* zsc     = (float*)(smem + LDS_ZSC);
    const unsigned char* cbws = ws + WS_CB;
    const float* cnorm = (const float*)(ws + WS_CNORM);

    if (tid == 0) *ambcnt = 0;

    // ---- issue async stage of chunk 0 into buf0 ----
    {
        const unsigned char* src = cbws + wv * 8192 + lane * 16;
        unsigned char* dst = smem + LDS_BUF + wv * 8192;   // wave-uniform dst
#pragma unroll
        for (int i = 0; i < 8; ++i)
            gload_lds16(src + i * 1024, dst + i * 1024);
    }

    // ---- stage cnb into LDS (overlaps with chunk-0 flight) ----
#pragma unroll
    for (int i = 0; i < 4; ++i)
        cnb_l[i * 256 + tid] = ((const float*)(ws + WS_CNB))[i * 256 + tid];

    // ---- z frags straight from global: wave owns pos wv*16..+15 ----
    // lane l: position l&15, dim-slot ks*4+(l>>4) (8 contiguous channels)
    short8 zfh[2], zfl[2];
    {
        const int pos = wv * 16 + l15;
#pragma unroll
        for (int ks = 0; ks < 2; ++ks) {
            const int sl = ks * 4 + lg;
            const float* zp = in + (((size_t)(b * CDIM + sl * 8)) << 12) + hw0 + pos;
            float f[8];
#pragma unroll
            for (int j = 0; j < 8; ++j) f[j] = zp[(size_t)j << 12];
            U4S8 H, L;
            uint32_t hp, lp;
            cvt_pair(f[0], f[1], hp, lp); H.u.x = hp; L.u.x = lp;
            cvt_pair(f[2], f[3], hp, lp); H.u.y = hp; L.u.y = lp;
            cvt_pair(f[4], f[5], hp, lp); H.u.z = hp; L.u.z = lp;
            cvt_pair(f[6], f[7], hp, lp); H.u.w = hp; L.u.w = lp;
            zfh[ks] = H.s; zfl[ks] = L.s;
        }
    }
    __syncthreads();    // chunk 0 + cnb ready

    const float finf = __uint_as_float(0x7F800000u);
    float m1 = finf, m2 = finf;

    int buf = 0;
    for (int c = 0; c < 8; ++c) {
        if (c < 7) {    // async stage next chunk into other buffer
            const unsigned char* src = cbws + (c + 1) * 32768 + wv * 8192 + lane * 16;
            unsigned char* dst = smem + LDS_BUF + (buf ^ 1) * 32768 + wv * 8192;
#pragma unroll
            for (int i = 0; i < 8; ++i)
                gload_lds16(src + i * 1024, dst + i * 1024);
        }

        const unsigned char* qb = smem + LDS_BUF + buf * 32768;
#pragma unroll
        for (int kt = 0; kt < 8; ++kt) {
            const int row = kt * 16 + l15;
            const int rsw = (row & 7) * 16;
            const int off0 = row * 128 + ((lg * 16) ^ rsw);
            const int off1 = row * 128 + (((4 + lg) * 16) ^ rsw);
            short8 ah0 = *(const short8*)(qb + off0);
            short8 al0 = *(const short8*)(qb + 16384 + off0);
            short8 ah1 = *(const short8*)(qb + off1);
            short8 al1 = *(const short8*)(qb + 16384 + off1);

            f32x4 acc = {0.f, 0.f, 0.f, 0.f};
            acc = __builtin_amdgcn_mfma_f32_16x16x32_bf16(al0, zfh[0], acc, 0, 0, 0);
            acc = __builtin_amdgcn_mfma_f32_16x16x32_bf16(ah0, zfl[0], acc, 0, 0, 0);
            acc = __builtin_amdgcn_mfma_f32_16x16x32_bf16(ah0, zfh[0], acc, 0, 0, 0);
            acc = __builtin_amdgcn_mfma_f32_16x16x32_bf16(al1, zfh[1], acc, 0, 0, 0);
            acc = __builtin_amdgcn_mfma_f32_16x16x32_bf16(ah1, zfl[1], acc, 0, 0, 0);
            acc = __builtin_amdgcn_mfma_f32_16x16x32_bf16(ah1, zfh[1], acc, 0, 0, 0);

            const int kb = c * 128 + kt * 16 + lg * 4;
            const f32x4 cn = *(const f32x4*)(cnb_l + kb);
#pragma unroll
            for (int r = 0; r < 4; ++r) {
                float s = fmaf(-2.0f, acc[r], cn[r]);
                float key = __uint_as_float(
                    (__float_as_uint(s) & 0xFFFFFC00u) | (uint32_t)(kb + r));
                m2 = fminf(m2, fmaxf(key, m1));
                m1 = fminf(m1, key);
            }
        }
        __syncthreads();    // next-chunk staging drained; buf free
        buf ^= 1;
    }

    // ---- merge the 4 k-lane-groups (lanes l15, +16, +32, +48) ----
#pragma unroll
    for (int off = 16; off <= 32; off <<= 1) {
        float o1 = __shfl_xor(m1, off);
        float o2 = __shfl_xor(m2, off);
        m2 = fminf(fminf(m2, o2), fmaxf(m1, o1));
        m1 = fminf(m1, o1);
    }

    // ---- finalize: lg==0 lanes own position wv*16+l15 ----
    if (lg == 0) {
        const int n = wv * 16 + l15;
        const uint32_t u1 = __float_as_uint(m1);
        const int idx = (int)(u1 & 1023u);
        sfin[n] = idx;
        out[n0g + n] = (float)idx;
        const float v1 = __uint_as_float(u1 & 0xFFFFFC00u);
        const float v2 = __uint_as_float(__float_as_uint(m2) & 0xFFFFFC00u);
        if (v2 - v1 < DELTA) {
            int p = atomicAdd(ambcnt, 1);
            amblist[p] = n;
        }
    }
    __syncthreads();

    // ---- exact rescreen, wave-parallel (validated numerics; z via LDS) ----
    const int namb = *ambcnt;
    for (int i = wv; i < namb; i += 4) {
        const int n = amblist[i];
        float zc = in[(((size_t)(b * CDIM + lane)) << 12) + hw0 + n];
        // bit-exact numpy pairwise znorm via shfl
        float sq = zc * zc;
        float accp = sq;
#pragma unroll
        for (int i2 = 1; i2 < 8; ++i2)
            accp = accp + __shfl(sq, i2 * 8 + (lane & 7));
        float t1 = accp + __shfl_xor(accp, 1);
        float t2 = t1 + __shfl_xor(t1, 2);
        float t3 = t2 + __shfl_xor(t2, 4);
        const float zn = __shfl(t3, 0);
        zsc[wv * 64 + lane] = zc;
        const float* zrow = &zsc[wv * 64];
        unsigned long long bestk = ~0ull;
        for (int j = 0; j < 16; ++j) {
            const int k = j * 64 + lane;
            const float4* e = (const float4*)(cb + (size_t)k * CDIM);
            float a0 = 0.f, a1 = 0.f, a2 = 0.f, a3 = 0.f;
#pragma unroll
            for (int i2 = 0; i2 < 4; ++i2) {
                float4 zz = *(const float4*)(zrow + i2 * 16);
                float4 z1 = *(const float4*)(zrow + i2 * 16 + 4);
                float4 z2 = *(const float4*)(zrow + i2 * 16 + 8);
                float4 z3 = *(const float4*)(zrow + i2 * 16 + 12);
                float4 v0 = e[i2 * 4 + 0];
                float4 v1 = e[i2 * 4 + 1];
                float4 v2 = e[i2 * 4 + 2];
                float4 v3 = e[i2 * 4 + 3];
                a0 = fmaf(zz.x, v0.x, a0); a0 = fmaf(zz.y, v0.y, a0);
                a0 = fmaf(zz.z, v0.z, a0); a0 = fmaf(zz.w, v0.w, a0);
                a1 = fmaf(z1.x, v1.x, a1); a1 = fmaf(z1.y, v1.y, a1);
                a1 = fmaf(z1.z, v1.z, a1); a1 = fmaf(z1.w, v1.w, a1);
                a2 = fmaf(z2.x, v2.x, a2); a2 = fmaf(z2.y, v2.y, a2);
                a2 = fmaf(z2.z, v2.z, a2); a2 = fmaf(z2.w, v2.w, a2);
                a3 = fmaf(z3.x, v3.x, a3); a3 = fmaf(z3.y, v3.y, a3);
                a3 = fmaf(z3.z, v3.z, a3); a3 = fmaf(z3.w, v3.w, a3);
            }
            float dot = (a0 + a1) + (a2 + a3);
            float t = zn + cnorm[k];   // fl(znorm + cnorm)
            float u = 2.0f * dot;      // fl(2*dot)
            float d = t - u;           // fl(t - u)
            unsigned long long key =
                ((unsigned long long)__float_as_uint(d) << 10) | (unsigned)k;
            bestk = key < bestk ? key : bestk;
        }
#pragma unroll
        for (int off = 32; off >= 1; off >>= 1) {
            unsigned long long o = shflxor64(bestk, off);
            bestk = o < bestk ? o : bestk;
        }
        if (lane == 0) {
            const int idx = (int)(bestk & 1023u);
            sfin[n] = idx;
            out[n0g + n] = (float)idx;
        }
    }
    __syncthreads();

    // ---- zqs epilogue: gather -> LDS tile (overlay buf) -> coalesced BCHW ----
    float (*tile)[65] = (float (*)[65])(smem);
    {
        const int p = tid >> 2, q4 = tid & 3;
        const int idx = sfin[p];
        const float4* row = (const float4*)(cb + (size_t)idx * CDIM) + q4 * 4;
#pragma unroll
        for (int i = 0; i < 4; ++i) {
            float4 v = row[i];
            const int cch = q4 * 16 + i * 4;
            tile[p][cch + 0] = v.x; tile[p][cch + 1] = v.y;
            tile[p][cch + 2] = v.z; tile[p][cch + 3] = v.w;
        }
    }
    __syncthreads();
    {
        float* zq = out + NPOS + (((size_t)b * CDIM) << 12) + hw0;
#pragma unroll
        for (int i = 0; i < 16; ++i) {
            const int cch = i * 4 + wv;
            zq[((size_t)cch << 12) + lane] = tile[lane][cch];
        }
    }
}

extern "C" void kernel_launch(void* const* d_in, const int* in_sizes, int n_in,
                              void* d_out, int out_size, void* d_ws, size_t ws_size,
                              hipStream_t stream) {
    const float* in = (const float*)d_in[0];   // 16*64*64*64
    const float* cb = (const float*)d_in[1];   // 1024*64
    float* out = (float*)d_out;                // 65536 + 4194304
    unsigned char* ws = (unsigned char*)d_ws;  // ~270 KB used

    vq_prep_kernel<<<NUM_K / 256, 256, 0, stream>>>(cb, ws);
    vq_main_kernel<<<NPOS / NPB, 256, 0, stream>>>(in, cb, ws, out);
}